// Round 3
// baseline (111.943 us; speedup 1.0000x reference)
//
#include <hip/hip_runtime.h>
#include <hip/hip_bf16.h>

// FuzzyContrastiveLearning: loss = mean_i[ -log(pos_i / (all_i + eps)) ]
// Symmetric Gram, triangular grid (2080 blocks), double-buffered LDS with
// prefetch-before-compute (T3 2-phase), T2 XOR swizzle (pre-swizzled source),
// underflow-skip epilogue. bf16 MFMA 16x16x32.

#define NROWS 8192
#define DIM   768
#define BM    128
#define BK    64
#define NK    (DIM / BK)              // 12
#define NBLK  (NROWS / BM)            // 64
#define NTILES (NBLK * (NBLK + 1) / 2) // 2080 (multiple of 8)
#define L2E   1.4426950408889634f

typedef __attribute__((ext_vector_type(8))) short short8;
typedef __attribute__((ext_vector_type(4))) float f32x4;

__device__ __forceinline__ void gload_lds16(const void* g, void* l) {
  __builtin_amdgcn_global_load_lds(
      (const __attribute__((address_space(1))) void*)g,
      (__attribute__((address_space(3))) void*)l, 16, 0, 0);
}

// Kernel 0: zero the (pos,all) accumulators (atomics need fresh zeros each call).
__global__ void zero_kernel(float* __restrict__ p) {
  p[blockIdx.x * 256 + threadIdx.x] = 0.f;
}

// Kernel 1: fp32 -> bf16 + row norms of the bf16-rounded values.
// One wave per row, float4 loads, ushort4 stores.
__global__ void prep_kernel(const float* __restrict__ x,
                            ushort* __restrict__ xb,
                            float* __restrict__ norms) {
  const int row  = blockIdx.x * 4 + (threadIdx.x >> 6);
  const int lane = threadIdx.x & 63;
  const float4* xr = (const float4*)(x + (size_t)row * DIM);
  ushort4* xbr = (ushort4*)(xb + (size_t)row * DIM);
  float acc = 0.f;
  #pragma unroll
  for (int c = 0; c < DIM / 4 / 64; ++c) {   // 3
    float4 v = xr[c * 64 + lane];
    union { __hip_bfloat16 b; ushort u; } cv;
    ushort4 o;
    cv.b = __float2bfloat16(v.x); o.x = cv.u; float f0 = __bfloat162float(cv.b);
    cv.b = __float2bfloat16(v.y); o.y = cv.u; float f1 = __bfloat162float(cv.b);
    cv.b = __float2bfloat16(v.z); o.z = cv.u; float f2 = __bfloat162float(cv.b);
    cv.b = __float2bfloat16(v.w); o.w = cv.u; float f3 = __bfloat162float(cv.b);
    acc += f0 * f0 + f1 * f1 + f2 * f2 + f3 * f3;
    xbr[c * 64 + lane] = o;
  }
  #pragma unroll
  for (int off = 32; off; off >>= 1) acc += __shfl_down(acc, off);
  if (lane == 0) norms[row] = acc;
}

// Kernel 2: one 128x128 upper-triangle tile per block. 256 thr = 2x2 waves.
__global__ __launch_bounds__(256, 2)
void fused_kernel(const ushort* __restrict__ xb,
                  const float* __restrict__ norms,
                  const int* __restrict__ labels,
                  float* __restrict__ part) {  // part[2*row]=pos, [2*row+1]=all
  // triangular decode with bijective XCD-chunk swizzle (NTILES % 8 == 0)
  const int orig = blockIdx.x;
  const int t = (orig & 7) * (NTILES / 8) + (orig >> 3);
  int bi = (int)(((double)(2 * NBLK + 1) -
                  sqrt((double)(2 * NBLK + 1) * (2 * NBLK + 1) - 8.0 * t)) * 0.5);
  while ((bi + 1) * (2 * NBLK - bi) / 2 <= t) ++bi;       // C(bi+1) <= t
  while (bi * (2 * NBLK - bi + 1) / 2 > t) --bi;          // C(bi)   >  t
  const int bj = bi + (t - bi * (2 * NBLK - bi + 1) / 2);
  const bool diag = (bi == bj);

  __shared__ ushort sA[2][BM * BK];
  __shared__ ushort sB[2][BM * BK];
  __shared__ float redr[2][BM][2];
  __shared__ float redc[2][BM][2];

  const int tid  = threadIdx.x;
  const int lane = tid & 63;
  const int wid  = tid >> 6;
  const int wm   = wid >> 1, wn = wid & 1;
  const int ln15 = lane & 15, hi4 = lane >> 4;
  const int brow = bi * BM;
  const int bcol = bj * BM;

  // precompute staging sources (T2: source slot XOR'd by row; LDS dest linear)
  const ushort* gA[4];
  const ushort* gB[4];
  int ldsOff[4];
  #pragma unroll
  for (int i = 0; i < 4; ++i) {
    int c = i * 256 + tid;
    int r = c >> 3;
    int so = ((c & 7) ^ (r & 7)) * 8;
    gA[i] = xb + (size_t)(brow + r) * DIM + so;
    gB[i] = xb + (size_t)(bcol + r) * DIM + so;
    ldsOff[i] = c * 8;
  }

  f32x4 zero = {0.f, 0.f, 0.f, 0.f};
  f32x4 acc[4][4];
  #pragma unroll
  for (int mi = 0; mi < 4; ++mi)
    #pragma unroll
    for (int nj = 0; nj < 4; ++nj) acc[mi][nj] = zero;

  // prologue: stage K-tile 0 into buffer 0
  #pragma unroll
  for (int i = 0; i < 4; ++i) {
    gload_lds16(gA[i], &sA[0][ldsOff[i]]);
    gload_lds16(gB[i], &sB[0][ldsOff[i]]);
  }
  __syncthreads();

  int cur = 0;
  for (int ks = 0; ks < NK; ++ks) {
    // prefetch next K-tile into the other buffer BEFORE compute
    if (ks + 1 < NK) {
      const int k0 = (ks + 1) * BK;
      #pragma unroll
      for (int i = 0; i < 4; ++i) {
        gload_lds16(gA[i] + k0, &sA[cur ^ 1][ldsOff[i]]);
        gload_lds16(gB[i] + k0, &sB[cur ^ 1][ldsOff[i]]);
      }
    }
    const ushort* bufA = sA[cur];
    const ushort* bufB = sB[cur];
    #pragma unroll
    for (int kk = 0; kk < 2; ++kk) {
      // row&7 == ln15&7; swizzled read slot
      const int slot = (((kk << 2) | hi4) ^ (ln15 & 7)) * 8;
      short8 af[4], bf[4];
      #pragma unroll
      for (int mi = 0; mi < 4; ++mi)
        af[mi] = *(const short8*)&bufA[(wm * 64 + mi * 16 + ln15) * BK + slot];
      #pragma unroll
      for (int nj = 0; nj < 4; ++nj)
        bf[nj] = *(const short8*)&bufB[(wn * 64 + nj * 16 + ln15) * BK + slot];
      #pragma unroll
      for (int mi = 0; mi < 4; ++mi)
        #pragma unroll
        for (int nj = 0; nj < 4; ++nj)
          acc[mi][nj] = __builtin_amdgcn_mfma_f32_16x16x32_bf16(
              af[mi], bf[nj], acc[mi][nj], 0, 0, 0);
    }
    __syncthreads();   // drains vmcnt (prefetch landed under compute) + lgkm
    cur ^= 1;
  }

  // ---- epilogue ----
  float hi2neg[16], lrF1[16], lrF0[16], hi2max[4];
  #pragma unroll
  for (int m = 0; m < 16; ++m) {
    int row = brow + wm * 64 + (m >> 2) * 16 + hi4 * 4 + (m & 3);
    hi2neg[m] = -0.5f * L2E * norms[row];
    float l = (float)labels[row];
    lrF1[m] = l; lrF0[m] = 1.0f - l;
  }
  #pragma unroll
  for (int mi = 0; mi < 4; ++mi)
    hi2max[mi] = fmaxf(fmaxf(hi2neg[mi * 4], hi2neg[mi * 4 + 1]),
                       fmaxf(hi2neg[mi * 4 + 2], hi2neg[mi * 4 + 3]));
  float hj2neg[4], fc1[4], fc0[4];
  int lc[4];
  #pragma unroll
  for (int nj = 0; nj < 4; ++nj) {
    int col = bcol + wn * 64 + nj * 16 + ln15;
    hj2neg[nj] = -0.5f * L2E * norms[col];
    lc[nj] = labels[col];
    fc1[nj] = (float)lc[nj]; fc0[nj] = 1.0f - fc1[nj];
  }

  float rs0[16], rs1[16], cs0[4], cs1[4];
  #pragma unroll
  for (int m = 0; m < 16; ++m) { rs0[m] = 0.f; rs1[m] = 0.f; }
  #pragma unroll
  for (int nj = 0; nj < 4; ++nj) { cs0[nj] = 0.f; cs1[nj] = 0.f; }

  #pragma unroll
  for (int mi = 0; mi < 4; ++mi)
    #pragma unroll
    for (int nj = 0; nj < 4; ++nj) {
      f32x4 a = acc[mi][nj];
      // underflow skip: if every t < -30, contributions are < 2^-30 (== 0.0f
      // after f32 underflow for this distance scale) -> identical to computing.
      float vmax = fmaxf(fmaxf(a[0], a[1]), fmaxf(a[2], a[3]));
      float tmax = fmaf(vmax, L2E, hi2max[mi]) + hj2neg[nj];
      if (tmax > -30.f) {
        #pragma unroll
        for (int r = 0; r < 4; ++r) {
          const int m = mi * 4 + r;
          float tt = fmaf(a[r], L2E, hi2neg[m]) + hj2neg[nj];
          float f = __builtin_amdgcn_exp2f(tt);
          rs1[m] = fmaf(f, fc1[nj], rs1[m]);     // row-sum split by COL label
          rs0[m] = fmaf(f, fc0[nj], rs0[m]);
          cs1[nj] = fmaf(f, lrF1[m], cs1[nj]);   // col-sum split by ROW label
          cs0[nj] = fmaf(f, lrF0[m], cs0[nj]);
        }
      }
    }

  // rows: reduce over 16 ln15 lanes, combine wn halves via LDS
  #pragma unroll
  for (int m = 0; m < 16; ++m) {
    float a = rs0[m], b = rs1[m];
    #pragma unroll
    for (int off = 1; off < 16; off <<= 1) {
      a += __shfl_xor(a, off);
      b += __shfl_xor(b, off);
    }
    rs0[m] = a; rs1[m] = b;
  }
  if (ln15 == 0) {
    #pragma unroll
    for (int m = 0; m < 16; ++m) {
      int row_l = wm * 64 + (m >> 2) * 16 + hi4 * 4 + (m & 3);
      float pos = (lrF1[m] != 0.f) ? rs1[m] : rs0[m];
      redr[wn][row_l][0] = pos;
      redr[wn][row_l][1] = rs0[m] + rs1[m];
    }
  }
  __syncthreads();
  if (tid < BM) {
    atomicAdd(&part[2 * (brow + tid)],     redr[0][tid][0] + redr[1][tid][0]);
    atomicAdd(&part[2 * (brow + tid) + 1], redr[0][tid][1] + redr[1][tid][1]);
  }

  // cols (off-diag only): transpose contribution f(j,i) to rows of block bj
  if (!diag) {
    #pragma unroll
    for (int nj = 0; nj < 4; ++nj) {
      float a = cs0[nj], b = cs1[nj];
      a += __shfl_xor(a, 16); a += __shfl_xor(a, 32);
      b += __shfl_xor(b, 16); b += __shfl_xor(b, 32);
      cs0[nj] = a; cs1[nj] = b;
    }
    if (hi4 == 0) {
      #pragma unroll
      for (int nj = 0; nj < 4; ++nj) {
        int col_l = wn * 64 + nj * 16 + ln15;
        float pos = lc[nj] ? cs1[nj] : cs0[nj];
        redc[wm][col_l][0] = pos;
        redc[wm][col_l][1] = cs0[nj] + cs1[nj];
      }
    }
    __syncthreads();
    if (tid < BM) {
      atomicAdd(&part[2 * (bcol + tid)],     redc[0][tid][0] + redc[1][tid][0]);
      atomicAdd(&part[2 * (bcol + tid) + 1], redc[0][tid][1] + redc[1][tid][1]);
    }
  }
}

// Kernel 3: per-row loss + mean.
__global__ void loss_kernel(const float* __restrict__ part,
                            float* __restrict__ out) {
  int tid = threadIdx.x;  // 1024
  float sum = 0.f;
  for (int row = tid; row < NROWS; row += 1024) {
    float pos = part[2 * row], all = part[2 * row + 1];
    sum += -logf(pos / (all + 1e-8f));
  }
  for (int off = 32; off; off >>= 1) sum += __shfl_down(sum, off);
  __shared__ float w[16];
  if ((tid & 63) == 0) w[tid >> 6] = sum;
  __syncthreads();
  if (tid == 0) {
    float t = 0.f;
    for (int i = 0; i < 16; ++i) t += w[i];
    out[0] = t / (float)NROWS;
  }
}

extern "C" void kernel_launch(void* const* d_in, const int* in_sizes, int n_in,
                              void* d_out, int out_size, void* d_ws, size_t ws_size,
                              hipStream_t stream) {
  const float* x      = (const float*)d_in[0];
  const int*   labels = (const int*)d_in[1];
  char* ws = (char*)d_ws;

  const size_t xb_bytes    = (size_t)NROWS * DIM * 2;   // 12,582,912
  const size_t norms_bytes = (size_t)NROWS * 4;         // 32,768
  const size_t part_bytes  = (size_t)NROWS * 2 * 4;     // 65,536
  if (ws_size < xb_bytes + norms_bytes + part_bytes) return;

  ushort* xb    = (ushort*)ws;
  float*  norms = (float*)(ws + xb_bytes);
  float*  part  = (float*)(ws + xb_bytes + norms_bytes);

  zero_kernel<<<NROWS * 2 / 256, 256, 0, stream>>>(part);
  prep_kernel<<<NROWS / 4, 256, 0, stream>>>(x, xb, norms);
  fused_kernel<<<NTILES, 256, 0, stream>>>(xb, norms, labels, part);
  loss_kernel<<<1, 1024, 0, stream>>>(part, (float*)d_out);
}

// Round 4
// 108.092 us; speedup vs baseline: 1.0356x; 1.0356x over previous
//
#include <hip/hip_runtime.h>
#include <hip/hip_bf16.h>

// FuzzyContrastiveLearning: loss = mean_i[ -log(pos_i / (all_i + eps)) ]
// Symmetric Gram, triangular 256^2 tiles (528 blocks), 8-phase K-schedule with
// counted vmcnt (T3+T4), T2 XOR swizzle, T5 setprio, underflow-skip epilogue.

#define NROWS 8192
#define DIM   768
#define BM    256
#define BK    64
#define NKT   (DIM / BK)               // 12
#define NBLK  (NROWS / BM)             // 32
#define NTILES (NBLK * (NBLK + 1) / 2) // 528 (divisible by 8)
#define L2E   1.4426950408889634f

typedef __attribute__((ext_vector_type(8))) short short8;
typedef __attribute__((ext_vector_type(4))) float f32x4;

__device__ __forceinline__ void gload_lds16(const void* g, void* l) {
  __builtin_amdgcn_global_load_lds(
      (const __attribute__((address_space(1))) void*)g,
      (__attribute__((address_space(3))) void*)l, 16, 0, 0);
}

// Kernel 1: fp32 -> bf16 + row norms of bf16-rounded values; first 16 blocks
// also zero the (pos,all) atomic accumulators.
__global__ void prep_kernel(const float* __restrict__ x,
                            ushort* __restrict__ xb,
                            float* __restrict__ norms,
                            float* __restrict__ part) {
  if (blockIdx.x < 16)
    ((float4*)part)[blockIdx.x * 256 + threadIdx.x] = make_float4(0.f, 0.f, 0.f, 0.f);
  const int row  = blockIdx.x * 4 + (threadIdx.x >> 6);
  const int lane = threadIdx.x & 63;
  const float4* xr = (const float4*)(x + (size_t)row * DIM);
  ushort4* xbr = (ushort4*)(xb + (size_t)row * DIM);
  float acc = 0.f;
  #pragma unroll
  for (int c = 0; c < DIM / 4 / 64; ++c) {   // 3
    float4 v = xr[c * 64 + lane];
    union { __hip_bfloat16 b; ushort u; } cv;
    ushort4 o;
    cv.b = __float2bfloat16(v.x); o.x = cv.u; float f0 = __bfloat162float(cv.b);
    cv.b = __float2bfloat16(v.y); o.y = cv.u; float f1 = __bfloat162float(cv.b);
    cv.b = __float2bfloat16(v.z); o.z = cv.u; float f2 = __bfloat162float(cv.b);
    cv.b = __float2bfloat16(v.w); o.w = cv.u; float f3 = __bfloat162float(cv.b);
    acc += f0 * f0 + f1 * f1 + f2 * f2 + f3 * f3;
    xbr[c * 64 + lane] = o;
  }
  #pragma unroll
  for (int off = 32; off; off >>= 1) acc += __shfl_down(acc, off);
  if (lane == 0) norms[row] = acc;
}

// Kernel 2: one 256x256 upper-triangle tile per block. 512 thr = 8 waves (2Mx4N).
__global__ __launch_bounds__(512, 2)
void fused_kernel(const ushort* __restrict__ xb,
                  const float* __restrict__ norms,
                  const int* __restrict__ labels,
                  float* __restrict__ part) {  // part[2*row]=pos, [2*row+1]=all
  // triangular decode with bijective XCD-chunk swizzle (NTILES % 8 == 0)
  const int orig = blockIdx.x;
  const int t = (orig & 7) * (NTILES / 8) + (orig >> 3);
  int bi = (int)(((double)(2 * NBLK + 1) -
                  sqrt((double)(2 * NBLK + 1) * (2 * NBLK + 1) - 8.0 * t)) * 0.5);
  while ((bi + 1) * (2 * NBLK - bi) / 2 <= t) ++bi;
  while (bi * (2 * NBLK - bi + 1) / 2 > t) --bi;
  const int bj = bi + (t - bi * (2 * NBLK - bi + 1) / 2);
  const bool diag = (bi == bj);

  __shared__ ushort sh[65536];   // 128 KiB: [A/B][dbuf][half][128*64]
  #define SH(ab, p, h) (sh + ((((ab) * 2 + (p)) * 2 + (h)) * 8192))

  const int tid  = threadIdx.x;
  const int lane = tid & 63;
  const int wid  = tid >> 6;        // 0..7
  const int wm   = wid >> 2;        // 0,1  -> rows wm*128..
  const int wn   = wid & 3;         // 0..3 -> cols wn*64..
  const int ln15 = lane & 15, hi4 = lane >> 4;
  const int slotx = ln15 & 7;
  const int brow = bi * BM, bcol = bj * BM;

  // staging: per thread 2 gload_lds per 128x64 half-tile; LDS dest linear,
  // global source slot XOR'd by row (T2, verified conflict-free R2/R3).
  const int c0 = tid, c1 = 512 + tid;
  const int r0 = c0 >> 3, r1 = c1 >> 3;
  const size_t gao0 = (size_t)r0 * DIM + ((c0 & 7) ^ (r0 & 7)) * 8;
  const size_t gao1 = (size_t)r1 * DIM + ((c1 & 7) ^ (r1 & 7)) * 8;
  const int d0 = c0 * 8, d1 = c1 * 8;
  const ushort* gA = xb + (size_t)brow * DIM;
  const ushort* gB = xb + (size_t)bcol * DIM;

  #define STAGE(ab, p, h, kt) do {                                         \
      const ushort* _g = ((ab) == 0 ? gA : gB) + (size_t)(h) * 128 * DIM + (kt) * BK; \
      ushort* _l = SH(ab, p, h);                                           \
      gload_lds16(_g + gao0, _l + d0);                                     \
      gload_lds16(_g + gao1, _l + d1);                                     \
    } while (0)

  f32x4 zero = {0.f, 0.f, 0.f, 0.f};
  f32x4 acc[8][4];
  #pragma unroll
  for (int mi = 0; mi < 8; ++mi)
    #pragma unroll
    for (int nj = 0; nj < 4; ++nj) acc[mi][nj] = zero;

  // prologue: stage K-tiles 0 and 1
  STAGE(0, 0, 0, 0); STAGE(0, 0, 1, 0); STAGE(1, 0, 0, 0); STAGE(1, 0, 1, 0);
  STAGE(0, 1, 0, 1); STAGE(0, 1, 1, 1); STAGE(1, 1, 0, 1); STAGE(1, 1, 1, 1);
  asm volatile("s_waitcnt vmcnt(8)" ::: "memory");   // kt0 landed
  __builtin_amdgcn_sched_barrier(0);
  __builtin_amdgcn_s_barrier();                       // globalize

  #define READ_A(mibase)                                                   \
    _Pragma("unroll")                                                      \
    for (int mi = 0; mi < 4; ++mi)                                         \
      _Pragma("unroll")                                                    \
      for (int kk = 0; kk < 2; ++kk)                                       \
        aR[mi][kk] = *(const short8*)&Ab[((mibase + mi) * 16 + ln15) * 64 +  \
                                         ((((kk << 2) | hi4) ^ slotx) << 3)];
  #define READ_B(njbase)                                                   \
    _Pragma("unroll")                                                      \
    for (int nq = 0; nq < 2; ++nq)                                         \
      _Pragma("unroll")                                                    \
      for (int kk = 0; kk < 2; ++kk)                                       \
        bR[njbase + nq][kk] = *(const short8*)&Bb[(brow7 + (njbase + nq) * 16 + ln15) * 64 + \
                                                  ((((kk << 2) | hi4) ^ slotx) << 3)];
  #define QUAD(mibase, njbase)                                             \
    __builtin_amdgcn_s_setprio(1);                                         \
    _Pragma("unroll")                                                      \
    for (int mi = 0; mi < 4; ++mi)                                         \
      _Pragma("unroll")                                                    \
      for (int nq = 0; nq < 2; ++nq)                                       \
        _Pragma("unroll")                                                  \
        for (int kk = 0; kk < 2; ++kk)                                     \
          acc[mibase + mi][njbase + nq] = __builtin_amdgcn_mfma_f32_16x16x32_bf16( \
              aR[mi][kk], bR[njbase + nq][kk], acc[mibase + mi][njbase + nq], 0, 0, 0); \
    __builtin_amdgcn_s_setprio(0);

  for (int kt = 0; kt < NKT; ++kt) {
    const int p = kt & 1;
    const ushort* Ab = SH(0, p, wm);        // wave reads only its A-half
    const ushort* Bb = SH(1, p, wn >> 1);   // and its B-half
    const int brow7 = (wn & 1) * 64;
    short8 aR[4][2], bR[4][2];

    // ph0: A[m0-3] + B[n0-1] reads -> quad(0,0)
    READ_A(0); READ_B(0);
    __builtin_amdgcn_s_barrier();
    QUAD(0, 0);
    __builtin_amdgcn_s_barrier();

    // ph1: B[n2-3] reads -> quad(0,2)   (B-region last read here)
    READ_B(2);
    __builtin_amdgcn_s_barrier();
    QUAD(0, 2);
    __builtin_amdgcn_s_barrier();

    // ph2: A[m4-7] reads; stage B(kt+2) into freed B-region -> quad(4,2)
    READ_A(4);
    if (kt <= NKT - 3) { STAGE(1, p, 0, kt + 2); STAGE(1, p, 1, kt + 2); }
    __builtin_amdgcn_s_barrier();
    QUAD(4, 2);
    __builtin_amdgcn_s_barrier();

    // ph3: stage A(kt+2) into freed A-region -> quad(4,0); counted vmcnt
    if (kt <= NKT - 3) { STAGE(0, p, 0, kt + 2); STAGE(0, p, 1, kt + 2); }
    __builtin_amdgcn_s_barrier();
    QUAD(4, 0);
    if (kt < NKT - 2) {
      asm volatile("s_waitcnt vmcnt(8)" ::: "memory");  // kt+1 landed, kt+2 in flight
    } else {
      asm volatile("s_waitcnt vmcnt(0)" ::: "memory");  // tail drain
    }
    __builtin_amdgcn_sched_barrier(0);
    __builtin_amdgcn_s_barrier();
  }

  // ---- epilogue ----
  __syncthreads();                       // LDS now reusable for reductions
  float* redr = (float*)sh;              // [4 wn][256 rows][2]
  float* redc = redr + 4 * 256 * 2;      // [2 wm][256 cols][2]

  float hj2neg[4], fc1[4], fc0[4];
  int lc[4];
  #pragma unroll
  for (int nj = 0; nj < 4; ++nj) {
    int col = bcol + wn * 64 + nj * 16 + ln15;
    hj2neg[nj] = -0.5f * L2E * norms[col];
    lc[nj] = labels[col];
    fc1[nj] = (float)lc[nj]; fc0[nj] = 1.0f - fc1[nj];
  }
  float cs0[4] = {0.f, 0.f, 0.f, 0.f}, cs1[4] = {0.f, 0.f, 0.f, 0.f};

  #pragma unroll
  for (int mi = 0; mi < 8; ++mi) {
    const int rbase = brow + wm * 128 + mi * 16 + hi4 * 4;
    float hi2neg[4], lr1[4];
    #pragma unroll
    for (int r = 0; r < 4; ++r) {
      hi2neg[r] = -0.5f * L2E * norms[rbase + r];
      lr1[r] = (float)labels[rbase + r];
    }
    float hmax = fmaxf(fmaxf(hi2neg[0], hi2neg[1]), fmaxf(hi2neg[2], hi2neg[3]));
    float rs0[4] = {0.f, 0.f, 0.f, 0.f}, rs1[4] = {0.f, 0.f, 0.f, 0.f};
    #pragma unroll
    for (int nj = 0; nj < 4; ++nj) {
      f32x4 a = acc[mi][nj];
      float vmax = fmaxf(fmaxf(a[0], a[1]), fmaxf(a[2], a[3]));
      float tmax = fmaf(vmax, L2E, hmax) + hj2neg[nj];
      if (tmax > -30.f) {   // else all f underflow to 0.0f exactly
        #pragma unroll
        for (int r = 0; r < 4; ++r) {
          float tt = fmaf(a[r], L2E, hi2neg[r]) + hj2neg[nj];
          float f = __builtin_amdgcn_exp2f(tt);
          rs1[r] = fmaf(f, fc1[nj], rs1[r]);       // row-sum, split by COL label
          rs0[r] = fmaf(f, fc0[nj], rs0[r]);
          cs1[nj] = fmaf(f, lr1[r], cs1[nj]);      // col-sum, split by ROW label
          cs0[nj] = fmaf(f, 1.0f - lr1[r], cs0[nj]);
        }
      }
    }
    // reduce rows over the 16 ln15 lanes
    #pragma unroll
    for (int r = 0; r < 4; ++r) {
      float a = rs0[r], b = rs1[r];
      #pragma unroll
      for (int off = 1; off < 16; off <<= 1) {
        a += __shfl_xor(a, off);
        b += __shfl_xor(b, off);
      }
      if (ln15 == 0) {
        int row_l = wm * 128 + mi * 16 + hi4 * 4 + r;
        float pos = (lr1[r] != 0.f) ? b : a;
        redr[(wn * 256 + row_l) * 2 + 0] = pos;
        redr[(wn * 256 + row_l) * 2 + 1] = a + b;
      }
    }
  }

  // reduce cols over the 4 hi4 lane-groups
  #pragma unroll
  for (int nj = 0; nj < 4; ++nj) {
    float a = cs0[nj], b = cs1[nj];
    a += __shfl_xor(a, 16); a += __shfl_xor(a, 32);
    b += __shfl_xor(b, 16); b += __shfl_xor(b, 32);
    if (hi4 == 0) {
      int col_l = wn * 64 + nj * 16 + ln15;
      float pos = lc[nj] ? b : a;
      redc[(wm * 256 + col_l) * 2 + 0] = pos;
      redc[(wm * 256 + col_l) * 2 + 1] = a + b;
    }
  }
  __syncthreads();

  if (tid < 256) {
    float pos = 0.f, all = 0.f;
    #pragma unroll
    for (int w = 0; w < 4; ++w) {
      pos += redr[(w * 256 + tid) * 2 + 0];
      all += redr[(w * 256 + tid) * 2 + 1];
    }
    atomicAdd(&part[2 * (brow + tid) + 0], pos);
    atomicAdd(&part[2 * (brow + tid) + 1], all);
    if (!diag) {   // transpose contribution f(j,i) to rows of block bj
      float posc = redc[tid * 2 + 0] + redc[(256 + tid) * 2 + 0];
      float allc = redc[tid * 2 + 1] + redc[(256 + tid) * 2 + 1];
      atomicAdd(&part[2 * (bcol + tid) + 0], posc);
      atomicAdd(&part[2 * (bcol + tid) + 1], allc);
    }
  }
}

// Kernel 3: per-row loss + mean.
__global__ void loss_kernel(const float* __restrict__ part,
                            float* __restrict__ out) {
  int tid = threadIdx.x;  // 1024
  float sum = 0.f;
  for (int row = tid; row < NROWS; row += 1024) {
    float pos = part[2 * row], all = part[2 * row + 1];
    sum += -logf(pos / (all + 1e-8f));
  }
  for (int off = 32; off; off >>= 1) sum += __shfl_down(sum, off);
  __shared__ float w[16];
  if ((tid & 63) == 0) w[tid >> 6] = sum;
  __syncthreads();
  if (tid == 0) {
    float t = 0.f;
    for (int i = 0; i < 16; ++i) t += w[i];
    out[0] = t / (float)NROWS;
  }
}

extern "C" void kernel_launch(void* const* d_in, const int* in_sizes, int n_in,
                              void* d_out, int out_size, void* d_ws, size_t ws_size,
                              hipStream_t stream) {
  const float* x      = (const float*)d_in[0];
  const int*   labels = (const int*)d_in[1];
  char* ws = (char*)d_ws;

  const size_t xb_bytes    = (size_t)NROWS * DIM * 2;   // 12,582,912
  const size_t norms_bytes = (size_t)NROWS * 4;         // 32,768
  const size_t part_bytes  = (size_t)NROWS * 2 * 4;     // 65,536
  if (ws_size < xb_bytes + norms_bytes + part_bytes) return;

  ushort* xb    = (ushort*)ws;
  float*  norms = (float*)(ws + xb_bytes);
  float*  part  = (float*)(ws + xb_bytes + norms_bytes);

  prep_kernel<<<NROWS / 4, 256, 0, stream>>>(x, xb, norms, part);
  fused_kernel<<<NTILES, 512, 0, stream>>>(xb, norms, labels, part);
  loss_kernel<<<1, 1024, 0, stream>>>(part, (float*)d_out);
}